// Round 5
// baseline (368.227 us; speedup 1.0000x reference)
//
#include <hip/hip_runtime.h>
#include <hip/hip_cooperative_groups.h>
#include <stdint.h>

#pragma clang fp contract(off)

#define BB 16
#define NN 25200
#define CCH 85
#define KTOP 512
#define NBKT 1024
#define CAP 1024

// ws layout:
//   conf  float[BB*NN] @ 0 (1,612,800 B)
//   meta  @ 1,703,936; per-batch stride 65,536:
//     sox4 @ +0 (8192) | bb4 @ +8192 (8192) | score @ +16384 (2048)
//     cls  @ +18432 (2048) | mask @ +20480 (32768)
#define META0 1703936
#define SB 65536

namespace cg = cooperative_groups;

__global__ __launch_bounds__(256) void k_conf(const float* __restrict__ x,
                                              float* __restrict__ conf) {
    __shared__ float tile[128 * CCH];
    const int blk = blockIdx.x;
    const int tid = threadIdx.x;

    const float4* src = (const float4*)x + (size_t)blk * 2720;
    float4* dst = (float4*)tile;
    for (int i = tid; i < 2720; i += 256) dst[i] = src[i];
    __syncthreads();

    const int r = tid >> 1;
    const int half = tid & 1;
    const float* row = tile + r * CCH;
    const float obj = row[4];

    float best = -1.0f;
    const float* cp = row + 5 + half * 40;
#pragma unroll
    for (int j = 0; j < 40; ++j) best = fmaxf(best, cp[j] * obj);
    best = fmaxf(best, __shfl_xor(best, 1));

    if (half == 0) {
        const int gr = blk * 128 + r;
        conf[gr] = ((obj > 0.01f) && (best > 0.01f)) ? best : -1.0f;
    }
}

__global__ __launch_bounds__(1024) void k_rest(const float* __restrict__ x,
                                               const float* __restrict__ target,
                                               const float* __restrict__ conf,
                                               char* __restrict__ meta,
                                               float* __restrict__ out) {
    __shared__ union {
        struct { unsigned hist[NBKT]; unsigned long long cand[CAP]; } p1;  // 12 KB
        unsigned mask[KTOP][16];                                           // 32 KB
    } um;
    __shared__ float4 sox[KTOP];      // P2: offset boxes; P3: plain boxes
    __shared__ float sarea[KTOP];
    __shared__ float sscore[KTOP];
    __shared__ int scls[KTOP];
    __shared__ unsigned wsum[16];
    __shared__ unsigned keep_words[16];
    __shared__ unsigned long long wred[16];
    __shared__ int sh_tstar, sh_cnt;

    cg::grid_group grid = cg::this_grid();
    const int tid = threadIdx.x;
    const int lane = tid & 63;
    const int bid = blockIdx.x;

    // ================= P1: selection (blocks 0..15, one batch each) =========
    if (bid < BB) {
        const int b = bid;
        char* mb = meta + (size_t)b * SB;
        const float4* cb4 = (const float4*)(conf + (size_t)b * NN);

        // hist
        um.p1.hist[tid] = 0u;
        if (tid == 0) { sh_tstar = 0; sh_cnt = 0; }
        __syncthreads();
        for (int i4 = tid; i4 < NN / 4; i4 += 1024) {
            float4 c4 = cb4[i4];
            float cs[4] = {c4.x, c4.y, c4.z, c4.w};
#pragma unroll
            for (int e = 0; e < 4; ++e) {
                float c = cs[e];
                if (c > 0.0f) {
                    int bk = (int)(c * 1024.0f);
                    if (bk > NBKT - 1) bk = NBKT - 1;
                    atomicAdd(&um.p1.hist[bk], 1u);
                }
            }
        }
        __syncthreads();

        // wave-hierarchical suffix scan (3 barriers total)
        unsigned v = um.p1.hist[tid];
        unsigned s = v;
#pragma unroll
        for (int d = 1; d < 64; d <<= 1) {
            unsigned t = __shfl_down(s, d);
            if (lane + d < 64) s += t;
        }
        if (lane == 0) wsum[tid >> 6] = s;
        __syncthreads();
        unsigned off = 0;
        for (int w = (tid >> 6) + 1; w < 16; ++w) off += wsum[w];
        unsigned S = s + off;                    // suffix sum from tid
        if (S >= KTOP && (S - v) < KTOP) sh_tstar = tid;   // unique
        __syncthreads();
        const int tstar = sh_tstar;

        // gather candidates (bucket >= tstar), wave-aggregated append
        for (int i4 = tid; i4 < NN / 4; i4 += 1024) {
            float4 c4 = cb4[i4];
            float cs[4] = {c4.x, c4.y, c4.z, c4.w};
#pragma unroll
            for (int e = 0; e < 4; ++e) {
                float c = cs[e];
                bool want = false;
                if (c > 0.0f) {
                    int bk = (int)(c * 1024.0f);
                    if (bk > NBKT - 1) bk = NBKT - 1;
                    want = (bk >= tstar);
                }
                unsigned long long bal = __ballot(want);
                int base = 0;
                if (lane == 0 && bal) base = atomicAdd(&sh_cnt, __popcll(bal));
                base = __shfl(base, 0);
                if (want) {
                    int pos = base + __popcll(bal & ((1ull << lane) - 1ull));
                    if (pos < CAP) {
                        unsigned bits = __float_as_uint(c);
                        um.p1.cand[pos] =
                            ((unsigned long long)bits << 32) | (unsigned)(~(i4 * 4 + e));
                    }
                }
            }
        }
        __syncthreads();
        const int M = min(sh_cnt, CAP);

        // hybrid bitonic sort, descending
        unsigned long long key = (tid < M) ? um.p1.cand[tid] : 0ull;
        __syncthreads();
        for (int kk = 2; kk <= CAP; kk <<= 1) {
            for (int j = kk >> 1; j > 0; j >>= 1) {
                unsigned long long partner;
                if (j >= 64) {
                    um.p1.cand[tid] = key;
                    __syncthreads();
                    partner = um.p1.cand[tid ^ j];
                    __syncthreads();
                } else {
                    partner = __shfl_xor(key, j);
                }
                bool desc = (tid & kk) == 0;
                bool lower = (tid & j) == 0;
                bool take_max = (lower == desc);
                bool pg = partner > key;
                key = (take_max == pg) ? partner : key;
            }
        }
        um.p1.cand[tid] = key;
        __syncthreads();

        // D: 2 threads/row — box + class argmax recompute for top-512
        const int rank = tid >> 1;
        const int half = tid & 1;
        unsigned long long rkey = um.p1.cand[rank];
        float sc = __uint_as_float((unsigned)(rkey >> 32));
        unsigned idx = ~((unsigned)rkey);
        const bool v2 = sc > 0.0f;
        float X1 = 0.f, Y1 = 0.f, X2 = 0.f, Y2 = 0.f;
        int cl = 0;
        if (v2) {
            const float* rw = x + ((size_t)b * NN + idx) * CCH;
            const float obj = rw[4];
            float bbest = -1.0f;
            int bi = 0;
            const float* cp = rw + 5 + half * 40;
#pragma unroll 8
            for (int j = 0; j < 40; ++j) {
                float p = cp[j] * obj;           // same rounded product as reference
                if (p > bbest) { bbest = p; bi = j; }
            }
            bi += half * 40;
            float ov = __shfl_xor(bbest, 1);
            int oi = __shfl_xor(bi, 1);
            if (half == 0) {
                if (ov > bbest) { bbest = ov; bi = oi; }  // tie -> lower class idx
                cl = bi;
                float cx = rw[0], cy = rw[1];
                float w = rw[2] * 0.5f, h = rw[3] * 0.5f;
                X1 = cx - w; Y1 = cy - h; X2 = cx + w; Y2 = cy + h;
            }
        }
        if (half == 0) {
            float offv = (float)cl * 4096.0f;
            ((float4*)mb)[rank] = make_float4(X1 + offv, Y1 + offv, X2 + offv, Y2 + offv);
            ((float4*)(mb + 8192))[rank] = make_float4(X1, Y1, X2, Y2);
            ((float*)(mb + 16384))[rank] = sc;
            ((int*)(mb + 18432))[rank] = cl;
        }
    }
    __threadfence();
    grid.sync();

    // ================= P2: mask slices (all 128 blocks) =====================
    {
        const int b = bid >> 3;
        const int slice = bid & 7;
        char* mb = meta + (size_t)b * SB;
        if (tid < KTOP) {
            float4 o = ((const float4*)mb)[tid];
            sox[tid] = o;
            sarea[tid] = (o.z - o.x) * (o.w - o.y);
        }
        __syncthreads();
        const int i = slice * 64 + (tid >> 4);
        const int w = tid & 15;
        unsigned bits = 0u;
        if ((w << 5) < i) {
            float4 bi4 = sox[i];
            float ai = sarea[i];
            const int jbase = w << 5;
            for (int jj = 0; jj < 32; ++jj) {
                int j = jbase + jj;
                float4 bj = sox[j];
                float lx = fmaxf(bi4.x, bj.x);
                float ly = fmaxf(bi4.y, bj.y);
                float rx = fminf(bi4.z, bj.z);
                float ry = fminf(bi4.w, bj.w);
                float inter = fmaxf(rx - lx, 0.0f) * fmaxf(ry - ly, 0.0f);
                float den = ai + sarea[j] - inter + 1e-9f;
                float iou = inter / den;
                unsigned hit = (unsigned)((j < i) & (iou > 0.5f));
                bits |= hit << jj;
            }
        }
        ((unsigned*)(mb + 20480))[slice * 1024 + tid] = bits;
    }
    __threadfence();
    grid.sync();

    // ================= P3: greedy NMS + output (blocks 0..15) ===============
    if (bid < BB) {
        const int b = bid;
        const char* mb = meta + (size_t)b * SB;
        const uint4* mg = (const uint4*)(mb + 20480);
        for (int p = tid; p < 2048; p += 1024) ((uint4*)um.mask)[p] = mg[p];
        if (tid < KTOP) {
            sox[tid] = ((const float4*)(mb + 8192))[tid];    // plain boxes
            sscore[tid] = ((const float*)(mb + 16384))[tid];
            scls[tid] = ((const int*)(mb + 18432))[tid];
        }
        __syncthreads();

        // F: greedy scan on wave 0, 2-deep prefetch
        if (tid < 64) {
            const int l15 = tid & 15;
            unsigned keepw = 0u;
            unsigned r0 = um.mask[0][l15], r1 = um.mask[1][l15];
            float s0 = sscore[0], s1 = sscore[1];
            for (int i = 0; i < KTOP; ++i) {
                unsigned r2 = 0u; float s2 = 0.f;
                if (i < KTOP - 2) { r2 = um.mask[i + 2][l15]; s2 = sscore[i + 2]; }
                unsigned long long bal = __ballot((r0 & keepw) != 0u);
                bool sup = (bal & 0xFFFFull) != 0ull;
                bool kept = (s0 > 0.0f) && !sup;
                if (kept && tid == (i >> 5)) keepw |= (1u << (i & 31));
                r0 = r1; r1 = r2; s0 = s1; s1 = s2;
            }
            if (tid < 16) keep_words[tid] = keepw;
        }
        __syncthreads();

        // G: masked argmax of IoU-with-target
        const float tb0 = target[0], tb1 = target[1], tb2 = target[2], tb3 = target[3];
        const int tcls = (int)target[5];
        float m = -1.0f;
        if (tid < KTOP) {
            bool kept = (keep_words[tid >> 5] >> (tid & 31)) & 1u;
            if (kept && scls[tid] == tcls) {
                float4 bx = sox[tid];
                float lx = fmaxf(bx.x, tb0);
                float ly = fmaxf(bx.y, tb1);
                float rx = fminf(bx.z, tb2);
                float ry = fminf(bx.w, tb3);
                float inter = fmaxf(rx - lx, 0.0f) * fmaxf(ry - ly, 0.0f);
                float areab = (bx.z - bx.x) * (bx.w - bx.y);
                float areat = (tb2 - tb0) * (tb3 - tb1);
                float den = areab + areat - inter + 1e-9f;
                m = inter / den;
            }
        }
        unsigned mbb = __float_as_uint(m);
        unsigned mono = (mbb & 0x80000000u) ? ~mbb : (mbb | 0x80000000u);
        unsigned long long rk = ((unsigned long long)mono << 32) | (unsigned)(~tid);
        for (int d = 32; d > 0; d >>= 1) {
            unsigned long long o = __shfl_xor(rk, d);
            if (o > rk) rk = o;
        }
        if ((tid & 63) == 0) wred[tid >> 6] = rk;
        __syncthreads();
        if (tid == 0) {
            unsigned long long bestk = wred[0];
            for (int i = 1; i < 16; ++i)
                if (wred[i] > bestk) bestk = wred[i];
            unsigned mono2 = (unsigned)(bestk >> 32);
            unsigned mbits = (mono2 & 0x80000000u) ? (mono2 & 0x7FFFFFFFu) : ~mono2;
            float mstar = __uint_as_float(mbits);
            int j = (int)(~((unsigned)bestk));
            out[b] = (mstar >= 0.0f) ? sscore[j] * mstar : 0.0f;
        }
    }
}

extern "C" void kernel_launch(void* const* d_in, const int* in_sizes, int n_in,
                              void* d_out, int out_size, void* d_ws, size_t ws_size,
                              hipStream_t stream) {
    const float* x = (const float*)d_in[0];
    const float* target = (const float*)d_in[1];
    float* out = (float*)d_out;
    float* conf = (float*)d_ws;
    char* meta = (char*)d_ws + META0;

    k_conf<<<dim3((BB * NN) / 128), dim3(256), 0, stream>>>(x, conf);

    void* args[5] = {(void*)&x, (void*)&target, (void*)&conf, (void*)&meta, (void*)&out};
    hipLaunchCooperativeKernel(reinterpret_cast<void*>(&k_rest), dim3(128), dim3(1024),
                               args, 0u, stream);
}

// Round 6
// 264.853 us; speedup vs baseline: 1.3903x; 1.3903x over previous
//
#include <hip/hip_runtime.h>
#include <stdint.h>

#pragma clang fp contract(off)

#define BB 16
#define NN 25200
#define CCH 85
#define KTOP 512
#define NBKT 1024
#define CAP 1024

// ws layout:
//   conf float[BB*NN] @ 0 (1,612,800 B)
//   clsw uint8[BB*NN] @ 1,612,800 (403,200 B)
//   meta @ 2,097,152; per-batch stride 65,536:
//     sox4 @ +0 (8192) | bb4 @ +8192 (8192) | score @ +16384 (2048)
//     cls  @ +18432 (2048) | mask @ +20480 (32768)
#define CLSW0 1612800
#define META0 2097152
#define SB 65536

__global__ __launch_bounds__(512) void k_conf(const float* __restrict__ x,
                                              float* __restrict__ conf,
                                              uint8_t* __restrict__ clsout) {
    __shared__ float tile[128 * CCH];
    const int blk = blockIdx.x;
    const int tid = threadIdx.x;

    // coalesced stage: 128 rows * 85 floats = 2720 float4
    const float4* src = (const float4*)x + (size_t)blk * 2720;
    float4* dst = (float4*)tile;
    for (int i = tid; i < 2720; i += 512) dst[i] = src[i];
    __syncthreads();

    const int r = tid >> 2;          // local row 0..127
    const int q = tid & 3;           // class quarter
    const float* row = tile + r * CCH;
    const float obj = row[4];

    float best = -1.0f;
    int bi = 0;
    const float* cp = row + 5 + q * 20;
#pragma unroll
    for (int j = 0; j < 20; ++j) {
        float p = cp[j] * obj;       // rounded product, same as reference
        if (p > best) { best = p; bi = j; }
    }
    bi += q * 20;

    // position-aware symmetric combine: (max, lowest index on ties)
    float ov = __shfl_xor(best, 1);
    int oi = __shfl_xor(bi, 1);
    if (ov > best || (ov == best && oi < bi)) { best = ov; bi = oi; }
    ov = __shfl_xor(best, 2);
    oi = __shfl_xor(bi, 2);
    if (ov > best || (ov == best && oi < bi)) { best = ov; bi = oi; }

    if (q == 0) {
        const int gr = blk * 128 + r;
        const bool valid = (obj > 0.01f) && (best > 0.01f);
        conf[gr] = valid ? best : -1.0f;
        clsout[gr] = (uint8_t)bi;
    }
}

__global__ __launch_bounds__(1024) void k_sel(const float* __restrict__ x,
                                              const uint8_t* __restrict__ clsw,
                                              const float* __restrict__ conf,
                                              char* __restrict__ meta) {
    __shared__ unsigned hist[NBKT];
    __shared__ unsigned long long cand[CAP];
    __shared__ unsigned wsum[16];
    __shared__ int sh_tstar, sh_cnt;

    const int b = blockIdx.x;
    const int tid = threadIdx.x;
    const int lane = tid & 63;
    const float4* cb4 = (const float4*)(conf + (size_t)b * NN);

    // ---- A: per-batch histogram (float4 loads) ----
    hist[tid] = 0u;
    if (tid == 0) { sh_tstar = 0; sh_cnt = 0; }
    __syncthreads();
    for (int i4 = tid; i4 < NN / 4; i4 += 1024) {
        float4 c4 = cb4[i4];
        float cs[4] = {c4.x, c4.y, c4.z, c4.w};
#pragma unroll
        for (int e = 0; e < 4; ++e) {
            float c = cs[e];
            if (c > 0.0f) {
                int bk = (int)(c * 1024.0f);
                if (bk > NBKT - 1) bk = NBKT - 1;
                atomicAdd(&hist[bk], 1u);
            }
        }
    }
    __syncthreads();

    // ---- wave-hierarchical suffix scan (3 barriers) ----
    unsigned v = hist[tid];
    unsigned s = v;
#pragma unroll
    for (int d = 1; d < 64; d <<= 1) {
        unsigned t = __shfl_down(s, d);
        if (lane + d < 64) s += t;
    }
    if (lane == 0) wsum[tid >> 6] = s;
    __syncthreads();
    unsigned off = 0;
    for (int w = (tid >> 6) + 1; w < 16; ++w) off += wsum[w];
    unsigned S = s + off;
    if (S >= KTOP && (S - v) < KTOP) sh_tstar = tid;
    __syncthreads();
    const int tstar = sh_tstar;

    // ---- B: gather candidates (bucket >= tstar), wave-aggregated append ----
    for (int i4 = tid; i4 < NN / 4; i4 += 1024) {
        float4 c4 = cb4[i4];
        float cs[4] = {c4.x, c4.y, c4.z, c4.w};
#pragma unroll
        for (int e = 0; e < 4; ++e) {
            float c = cs[e];
            bool want = false;
            if (c > 0.0f) {
                int bk = (int)(c * 1024.0f);
                if (bk > NBKT - 1) bk = NBKT - 1;
                want = (bk >= tstar);
            }
            unsigned long long bal = __ballot(want);
            int base = 0;
            if (lane == 0 && bal) base = atomicAdd(&sh_cnt, __popcll(bal));
            base = __shfl(base, 0);
            if (want) {
                int pos = base + __popcll(bal & ((1ull << lane) - 1ull));
                if (pos < CAP) {
                    unsigned bits = __float_as_uint(c);
                    cand[pos] = ((unsigned long long)bits << 32) | (unsigned)(~(i4 * 4 + e));
                }
            }
        }
    }
    __syncthreads();
    const int M = min(sh_cnt, CAP);

    // ---- C: hybrid bitonic sort, descending; 1 key/thread in register ----
    unsigned long long key = (tid < M) ? cand[tid] : 0ull;
    __syncthreads();
    for (int kk = 2; kk <= CAP; kk <<= 1) {
        for (int j = kk >> 1; j > 0; j >>= 1) {
            unsigned long long partner;
            if (j >= 64) {
                cand[tid] = key;
                __syncthreads();
                partner = cand[tid ^ j];
                __syncthreads();
            } else {
                partner = __shfl_xor(key, j);
            }
            bool desc = (tid & kk) == 0;
            bool lower = (tid & j) == 0;
            bool take_max = (lower == desc);
            bool pg = partner > key;
            key = (take_max == pg) ? partner : key;
        }
    }

    // ---- D: top-512 -> boxes/scores/cls into per-batch meta region ----
    char* mb = meta + (size_t)b * SB;
    if (tid < KTOP) {
        float sc = __uint_as_float((unsigned)(key >> 32));
        unsigned idx = ~((unsigned)key);
        bool v2 = sc > 0.0f;
        float X1 = 0.f, Y1 = 0.f, X2 = 0.f, Y2 = 0.f;
        int cl = 0;
        if (v2) {
            const float* rw = x + ((size_t)b * NN + idx) * CCH;
            float cx = rw[0], cy = rw[1];
            float w = rw[2] * 0.5f, h = rw[3] * 0.5f;
            X1 = cx - w; Y1 = cy - h; X2 = cx + w; Y2 = cy + h;
            cl = clsw[(size_t)b * NN + idx];
        }
        float offv = (float)cl * 4096.0f;
        ((float4*)mb)[tid] = make_float4(X1 + offv, Y1 + offv, X2 + offv, Y2 + offv);
        ((float4*)(mb + 8192))[tid] = make_float4(X1, Y1, X2, Y2);
        ((float*)(mb + 16384))[tid] = sc;
        ((int*)(mb + 18432))[tid] = cl;
    }
}

__global__ __launch_bounds__(1024) void k_mask(char* __restrict__ meta) {
    __shared__ float4 sox[KTOP];
    __shared__ float sarea[KTOP];
    const int slice = blockIdx.x;     // 0..7
    const int b = blockIdx.y;         // 0..15
    const int tid = threadIdx.x;
    char* mb = meta + (size_t)b * SB;

    if (tid < KTOP) {
        float4 o = ((const float4*)mb)[tid];
        sox[tid] = o;
        sarea[tid] = (o.z - o.x) * (o.w - o.y);
    }
    __syncthreads();

    const int i = slice * 64 + (tid >> 4);
    const int w = tid & 15;
    unsigned bits = 0u;
    if ((w << 5) < i) {
        float4 bi4 = sox[i];
        float ai = sarea[i];
        const int jbase = w << 5;
        for (int jj = 0; jj < 32; ++jj) {
            int j = jbase + jj;
            float4 bj = sox[j];
            float lx = fmaxf(bi4.x, bj.x);
            float ly = fmaxf(bi4.y, bj.y);
            float rx = fminf(bi4.z, bj.z);
            float ry = fminf(bi4.w, bj.w);
            float inter = fmaxf(rx - lx, 0.0f) * fmaxf(ry - ly, 0.0f);
            float den = ai + sarea[j] - inter + 1e-9f;
            float iou = inter / den;
            unsigned hit = (unsigned)((j < i) & (iou > 0.5f));
            bits |= hit << jj;
        }
    }
    ((unsigned*)(mb + 20480))[slice * 1024 + tid] = bits;
}

__global__ __launch_bounds__(1024) void k_nms(const float* __restrict__ target,
                                              const char* __restrict__ meta,
                                              float* __restrict__ out) {
    __shared__ unsigned smask[KTOP][16];     // 32 KB
    __shared__ float4 sbb[KTOP];             // 8 KB
    __shared__ float sscore[KTOP];
    __shared__ int scls[KTOP];
    __shared__ unsigned keep_words[16];
    __shared__ unsigned long long wred[16];

    const int b = blockIdx.x;
    const int tid = threadIdx.x;
    const char* mb = meta + (size_t)b * SB;

    const uint4* mg = (const uint4*)(mb + 20480);
    for (int p = tid; p < 2048; p += 1024) ((uint4*)smask)[p] = mg[p];
    if (tid < KTOP) {
        sbb[tid] = ((const float4*)(mb + 8192))[tid];
        sscore[tid] = ((const float*)(mb + 16384))[tid];
        scls[tid] = ((const int*)(mb + 18432))[tid];
    }
    __syncthreads();

    // ---- F: greedy scan on wave 0, 2-deep prefetch ----
    if (tid < 64) {
        const int l15 = tid & 15;
        unsigned keepw = 0u;
        unsigned r0 = smask[0][l15], r1 = smask[1][l15];
        float s0 = sscore[0], s1 = sscore[1];
        for (int i = 0; i < KTOP; ++i) {
            unsigned r2 = 0u; float s2 = 0.f;
            if (i < KTOP - 2) { r2 = smask[i + 2][l15]; s2 = sscore[i + 2]; }
            unsigned long long bal = __ballot((r0 & keepw) != 0u);
            bool sup = (bal & 0xFFFFull) != 0ull;
            bool kept = (s0 > 0.0f) && !sup;
            if (kept && tid == (i >> 5)) keepw |= (1u << (i & 31));
            r0 = r1; r1 = r2; s0 = s1; s1 = s2;
        }
        if (tid < 16) keep_words[tid] = keepw;
    }
    __syncthreads();

    // ---- G: masked argmax of IoU-with-target, output ----
    const float tb0 = target[0], tb1 = target[1], tb2 = target[2], tb3 = target[3];
    const int tcls = (int)target[5];
    float m = -1.0f;
    if (tid < KTOP) {
        bool kept = (keep_words[tid >> 5] >> (tid & 31)) & 1u;
        if (kept && scls[tid] == tcls) {
            float4 bx = sbb[tid];
            float lx = fmaxf(bx.x, tb0);
            float ly = fmaxf(bx.y, tb1);
            float rx = fminf(bx.z, tb2);
            float ry = fminf(bx.w, tb3);
            float inter = fmaxf(rx - lx, 0.0f) * fmaxf(ry - ly, 0.0f);
            float areab = (bx.z - bx.x) * (bx.w - bx.y);
            float areat = (tb2 - tb0) * (tb3 - tb1);
            float den = areab + areat - inter + 1e-9f;
            m = inter / den;
        }
    }
    unsigned mbb = __float_as_uint(m);
    unsigned mono = (mbb & 0x80000000u) ? ~mbb : (mbb | 0x80000000u);
    unsigned long long rk = ((unsigned long long)mono << 32) | (unsigned)(~tid);
    for (int d = 32; d > 0; d >>= 1) {
        unsigned long long o = __shfl_xor(rk, d);
        if (o > rk) rk = o;
    }
    if ((tid & 63) == 0) wred[tid >> 6] = rk;
    __syncthreads();
    if (tid == 0) {
        unsigned long long bestk = wred[0];
        for (int i = 1; i < 16; ++i)
            if (wred[i] > bestk) bestk = wred[i];
        unsigned mono2 = (unsigned)(bestk >> 32);
        unsigned mbits = (mono2 & 0x80000000u) ? (mono2 & 0x7FFFFFFFu) : ~mono2;
        float mstar = __uint_as_float(mbits);
        int j = (int)(~((unsigned)bestk));
        out[b] = (mstar >= 0.0f) ? sscore[j] * mstar : 0.0f;
    }
}

extern "C" void kernel_launch(void* const* d_in, const int* in_sizes, int n_in,
                              void* d_out, int out_size, void* d_ws, size_t ws_size,
                              hipStream_t stream) {
    const float* x = (const float*)d_in[0];
    const float* target = (const float*)d_in[1];
    float* out = (float*)d_out;

    char* ws = (char*)d_ws;
    float* conf = (float*)ws;
    uint8_t* clsw = (uint8_t*)(ws + CLSW0);
    char* meta = ws + META0;

    k_conf<<<dim3((BB * NN) / 128), dim3(512), 0, stream>>>(x, conf, clsw);
    k_sel<<<dim3(BB), dim3(1024), 0, stream>>>(x, clsw, conf, meta);
    k_mask<<<dim3(8, BB), dim3(1024), 0, stream>>>(meta);
    k_nms<<<dim3(BB), dim3(1024), 0, stream>>>(target, meta, out);
}